// Round 10
// baseline (20886.060 us; speedup 1.0000x reference)
//
#include <hip/hip_runtime.h>
#include <math.h>

#define BB 32
#define TT 2048
#define FF 16
#define CC 17
#define HH 64

typedef float v2f __attribute__((ext_vector_type(2)));
typedef float v4f __attribute__((ext_vector_type(4)));
typedef _Float16 h2 __attribute__((ext_vector_type(2)));

__device__ __forceinline__ float rl(float v, int lane) {
    return __int_as_float(__builtin_amdgcn_readlane(__float_as_int(v), lane));
}
__device__ __forceinline__ unsigned rlu(unsigned v, int lane) {
    return (unsigned)__builtin_amdgcn_readlane((int)v, lane);
}
__device__ __forceinline__ float uf(float v) {
    return __int_as_float(__builtin_amdgcn_readfirstlane(__float_as_int(v)));
}
__device__ __forceinline__ float ftanh(float x) {
    float e = __builtin_amdgcn_exp2f(x * 2.88539008177792681472f); // exp(2x)
    return 1.0f - 2.0f * __builtin_amdgcn_rcpf(e + 1.0f);
}
__device__ __forceinline__ float fdot2u(unsigned a, unsigned b, float c) {
    return __builtin_amdgcn_fdot2(__builtin_bit_cast(h2, a),
                                  __builtin_bit_cast(h2, b), c, false);
}
// pack (a,b) to f16x2, scaled by 2^8 (weights); RN; init-time only
__device__ __forceinline__ unsigned packw(float a, float b) {
    h2 p; p.x = (_Float16)(a * 256.0f); p.y = (_Float16)(b * 256.0f);
    return __builtin_bit_cast(unsigned, p);
}
// LDS-only barrier: no vmcnt(0) drain.
__device__ __forceinline__ void bar_lds() {
    asm volatile("s_waitcnt lgkmcnt(0)\n\ts_barrier" ::: "memory");
}
#define PIN(v) asm volatile("" : "+v"(v))

// R9 skeleton dualized: one block serves TWO batch elements in the same
// instruction stream. Weights (f16-packed, ~91 regs) are shared; every
// barrier / LDS-latency window / SGPR-readlane hazard now serves two
// independent dependency chains, and the combine reads are v2f/v4f (one
// LDS instruction serves both elements). R5 failed this shape only via
// register spills from 128 pinned f32 out-weights; R9's compact state
// leaves headroom.
__attribute__((amdgpu_waves_per_eu(2, 2)))
__launch_bounds__(512)
__global__ void ncde_main(const float* __restrict__ x,
                          const float* __restrict__ wi1, const float* __restrict__ bi1,
                          const float* __restrict__ wi2, const float* __restrict__ bi2,
                          const float* __restrict__ w_in, const float* __restrict__ b_in,
                          const float* __restrict__ w_hid, const float* __restrict__ b_hid,
                          const float* __restrict__ w_out, const float* __restrict__ b_out,
                          float* __restrict__ zT)
{
    const int bid = blockIdx.x;
    const int eA = 2 * bid, eB = 2 * bid + 1;
    const int tid = threadIdx.x;
    const int w   = tid >> 6;
    const int l   = tid & 63;

    __shared__ v2f ph[4][8][64];    // (A,B) hidden partials [layer][wave][h]
    __shared__ v4f pgq[8][64];      // (pgA, a16A, pgB, a16B) partials per wave

    // ---- hidden weights: wave w owns k-slice [8w,8w+8), packed 4 u32/layer ----
    unsigned whp[4][4];
    #pragma unroll
    for (int kk = 0; kk < 4; ++kk) {
        int k = 8 * w + 2 * kk;
        whp[0][kk] = packw(w_in[k * HH + l],               w_in[(k + 1) * HH + l]);
        whp[1][kk] = packw(w_hid[(0 * HH + k) * HH + l],   w_hid[(0 * HH + k + 1) * HH + l]);
        whp[2][kk] = packw(w_hid[(1 * HH + k) * HH + l],   w_hid[(1 * HH + k + 1) * HH + l]);
        whp[3][kk] = packw(w_hid[(2 * HH + k) * HH + l],   w_hid[(2 * HH + k + 1) * HH + l]);
    }
    float bfold[4];
    bfold[0] = (w == 0) ? b_in[l] : 0.0f;
    bfold[1] = (w == 0) ? b_hid[0 * HH + l] : 0.0f;
    bfold[2] = (w == 0) ? b_hid[1 * HH + l] : 0.0f;
    bfold[3] = (w == 0) ? b_hid[2 * HH + l] : 0.0f;

    // ---- out-layer weights (cols c0,c1 per wave + c16 k-slice), packed ----
    const int c0 = 2 * w, c1 = 2 * w + 1;
    unsigned wo0p[32], wo1p[32], w16p[4];
    #pragma unroll
    for (int j = 0; j < 32; ++j) {
        wo0p[j] = packw(w_out[(2 * j) * (CC * HH) + l * CC + c0],
                        w_out[(2 * j + 1) * (CC * HH) + l * CC + c0]);
        wo1p[j] = packw(w_out[(2 * j) * (CC * HH) + l * CC + c1],
                        w_out[(2 * j + 1) * (CC * HH) + l * CC + c1]);
    }
    #pragma unroll
    for (int jj = 0; jj < 4; ++jj)
        w16p[jj] = packw(w_out[(8 * w + 2 * jj) * (CC * HH) + l * CC + 16],
                         w_out[(8 * w + 2 * jj + 1) * (CC * HH) + l * CC + 16]);
    float bo0  = b_out[l * CC + c0];
    float bo1  = b_out[l * CC + c1];
    float bo16 = b_out[l * CC + 16];

    #pragma unroll
    for (int j = 0; j < 32; ++j) { PIN(wo0p[j]); PIN(wo1p[j]); }
    #pragma unroll
    for (int jj = 0; jj < 4; ++jj) PIN(w16p[jj]);
    #pragma unroll
    for (int lay = 0; lay < 4; ++lay) {
        PIN(whp[lay][0]); PIN(whp[lay][1]); PIN(whp[lay][2]); PIN(whp[lay][3]);
        PIN(bfold[lay]);
    }
    PIN(bo0); PIN(bo1); PIN(bo16);

    // ---- z0 for both elements ----
    float zA, zB;
    {
        float h0A = bi1[l], h0B = h0A;
        #pragma unroll
        for (int c = 1; c < CC; ++c) {
            float w1 = wi1[c * HH + l];
            h0A = fmaf(x[(size_t)eA * TT * FF + (c - 1)], w1, h0A);
            h0B = fmaf(x[(size_t)eB * TT * FF + (c - 1)], w1, h0B);
        }
        h0A = fmaxf(h0A, 0.0f); h0B = fmaxf(h0B, 0.0f);
        zA = bi2[l]; zB = zA;
        #pragma unroll
        for (int k = 0; k < 64; ++k) {
            float w2 = wi2[k * HH + l];
            zA = fmaf(rl(h0A, k), w2, zA);
            zB = fmaf(rl(h0B, k), w2, zB);
        }
    }
    if (w == 0) zT[(size_t)eA * TT * HH + l] = zA;
    if (w == 1) zT[(size_t)eB * TT * HH + l] = zB;

    // pack v*2^-8 into f16x2; every lane ends holding pair (v[2j],v[2j+1]), j=l>>1
    auto packb = [&](float v) -> unsigned {
        float hs = v * 0.00390625f;
        float pr = __shfl_xor(hs, 1);
        float a  = (l & 1) ? pr : hs;
        float bb = (l & 1) ? hs : pr;
        return __builtin_bit_cast(unsigned, __builtin_amdgcn_cvt_pkrtz(a, bb));
    };

    // ---- fused dual g() ----
    auto G2 = [&](float ziA, float ziB,
                  float xa0, float xa1, float xa16,
                  float xb0, float xb1, float xb16) -> v2f {
        float cA = ziA, cB = ziB;
        #pragma unroll
        for (int layer = 0; layer < 4; ++layer) {
            unsigned hpA = packb(cA), hpB = packb(cB);
            float aA0 = bfold[layer], aA1 = 0.0f;
            float aB0 = bfold[layer], aB1 = 0.0f;
            #pragma unroll
            for (int jj = 0; jj < 4; jj += 2) {
                unsigned sA0 = rlu(hpA, 8 * w + 2 * jj);
                unsigned sB0 = rlu(hpB, 8 * w + 2 * jj);
                unsigned sA1 = rlu(hpA, 8 * w + 2 * jj + 2);
                unsigned sB1 = rlu(hpB, 8 * w + 2 * jj + 2);
                aA0 = fdot2u(sA0, whp[layer][jj],     aA0);
                aB0 = fdot2u(sB0, whp[layer][jj],     aB0);
                aA1 = fdot2u(sA1, whp[layer][jj + 1], aA1);
                aB1 = fdot2u(sB1, whp[layer][jj + 1], aB1);
            }
            ph[layer][w][l] = (v2f){ aA0 + aA1, aB0 + aB1 };
            bar_lds();
            v2f r0 = ph[layer][0][l], r1 = ph[layer][1][l];
            v2f r2 = ph[layer][2][l], r3 = ph[layer][3][l];
            v2f r4 = ph[layer][4][l], r5 = ph[layer][5][l];
            v2f r6 = ph[layer][6][l], r7 = ph[layer][7][l];
            v2f s = ((r0 + r1) + (r2 + r3)) + ((r4 + r5) + (r6 + r7));
            cA = fmaxf(s.x, 0.0f);
            cB = fmaxf(s.y, 0.0f);
        }
        // out layer, in-wave from cA/cB (every wave holds full h per element)
        unsigned hpA = packb(cA), hpB = packb(cB);
        float uA0 = 0.f, uA1 = 0.f, uB0 = 0.f, uB1 = 0.f;
        #pragma unroll
        for (int j = 0; j < 32; ++j) {
            unsigned sA = rlu(hpA, 2 * j);
            unsigned sB = rlu(hpB, 2 * j);
            uA0 = fdot2u(sA, wo0p[j], uA0);
            uB0 = fdot2u(sB, wo0p[j], uB0);
            uA1 = fdot2u(sA, wo1p[j], uA1);
            uB1 = fdot2u(sB, wo1p[j], uB1);
        }
        float aA16 = 0.f, aB16 = 0.f;
        #pragma unroll
        for (int jj = 0; jj < 4; ++jj) {
            unsigned sA = rlu(hpA, 8 * w + 2 * jj);
            unsigned sB = rlu(hpB, 8 * w + 2 * jj);
            aA16 = fdot2u(sA, w16p[jj], aA16);
            aB16 = fdot2u(sB, w16p[jj], aB16);
        }
        float pgA = ftanh(uA0 + bo0) * xa0 + ftanh(uA1 + bo1) * xa1;
        float pgB = ftanh(uB0 + bo0) * xb0 + ftanh(uB1 + bo1) * xb1;
        pgq[w][l] = (v4f){ pgA, aA16, pgB, aB16 };
        bar_lds();
        v4f s0 = pgq[0][l], s1 = pgq[1][l], s2 = pgq[2][l], s3 = pgq[3][l];
        v4f s4 = pgq[4][l], s5 = pgq[5][l], s6 = pgq[6][l], s7 = pgq[7][l];
        v4f st = ((s0 + s1) + (s2 + s3)) + ((s4 + s5) + (s6 + s7));
        return (v2f){ fmaf(ftanh(st.y + bo16), xa16, st.x),
                      fmaf(ftanh(st.w + bo16), xb16, st.z) };
    };

    // ---- time scan (uniform x scalars in SGPRs via uf) ----
    const float* xA = x + (size_t)eA * TT * FF;
    const float* xB = x + (size_t)eB * TT * FF;
    const bool hasc0 = (w != 0);
    const int  f0 = 2 * w - 1;
    const int  f1 = 2 * w;

    float xpA0 = hasc0 ? uf(xA[f0]) : 0.0f, xpA1 = uf(xA[f1]), xpA16 = uf(xA[15]);
    float xpB0 = hasc0 ? uf(xB[f0]) : 0.0f, xpB1 = uf(xB[f1]), xpB16 = uf(xB[15]);
    float xnA0 = hasc0 ? uf(xA[FF + f0]) : 0.0f, xnA1 = uf(xA[FF + f1]), xnA16 = uf(xA[FF + 15]);
    float xnB0 = hasc0 ? uf(xB[FF + f0]) : 0.0f, xnB1 = uf(xB[FF + f1]), xnB16 = uf(xB[FF + 15]);
    float dcA0 = hasc0 ? (xnA0 - xpA0) : 1.0f, dcA1 = xnA1 - xpA1, dcA16 = xnA16 - xpA16;
    float dcB0 = hasc0 ? (xnB0 - xpB0) : 1.0f, dcB1 = xnB1 - xpB1, dcB16 = xnB16 - xpB16;
    float dpA0 = dcA0, dpA1 = dcA1, dpA16 = dcA16;
    float dpB0 = dcB0, dpB1 = dcB1, dpB16 = dcB16;
    xpA0 = xnA0; xpA1 = xnA1; xpA16 = xnA16;
    xpB0 = xnB0; xpB1 = xnB1; xpB16 = xnB16;

    #pragma unroll 1
    for (int t = 0; t < TT - 1; ++t) {
        const float f43 = 4.0f / 3.0f;
        float x2A0 = dpA0 + f43 * (dcA0 - dpA0);
        float x2A1 = dpA1 + f43 * (dcA1 - dpA1);
        float x2A16 = dpA16 + f43 * (dcA16 - dpA16);
        float x2B0 = dpB0 + f43 * (dcB0 - dpB0);
        float x2B1 = dpB1 + f43 * (dcB1 - dpB1);
        float x2B16 = dpB16 + f43 * (dcB16 - dpB16);

        int tn = (t + 2 < TT) ? (t + 2) : (TT - 1);
        float ynA0 = hasc0 ? uf(xA[tn * FF + f0]) : 0.0f;
        float ynA1 = uf(xA[tn * FF + f1]);
        float ynA16 = uf(xA[tn * FF + 15]);
        float ynB0 = hasc0 ? uf(xB[tn * FF + f0]) : 0.0f;
        float ynB1 = uf(xB[tn * FF + f1]);
        float ynB16 = uf(xB[tn * FF + 15]);

        v2f k1 = G2(zA, zB, dpA0, dpA1, dpA16, dpB0, dpB1, dpB16);
        v2f k2 = G2(zA + k1.x * (1.0f / 3.0f), zB + k1.y * (1.0f / 3.0f),
                    dcA0, dcA1, dcA16, dcB0, dcB1, dcB16);
        v2f k3 = G2(zA + (k2.x - k1.x * (1.0f / 3.0f)), zB + (k2.y - k1.y * (1.0f / 3.0f)),
                    x2A0, x2A1, x2A16, x2B0, x2B1, x2B16);
        v2f k4 = G2(zA + (k1.x - k2.x + k3.x), zB + (k1.y - k2.y + k3.y),
                    dcA0, dcA1, dcA16, dcB0, dcB1, dcB16);
        zA += 0.125f * (k1.x + 3.0f * (k2.x + k3.x) + k4.x);
        zB += 0.125f * (k1.y + 3.0f * (k2.y + k3.y) + k4.y);

        if (w == 0) zT[((size_t)eA * TT + t + 1) * HH + l] = zA;
        if (w == 1) zT[((size_t)eB * TT + t + 1) * HH + l] = zB;

        dpA0 = dcA0; dpA1 = dcA1; dpA16 = dcA16;
        dpB0 = dcB0; dpB1 = dcB1; dpB16 = dcB16;
        dcA0 = hasc0 ? (ynA0 - xpA0) : 1.0f;
        dcA1 = ynA1 - xpA1; dcA16 = ynA16 - xpA16;
        dcB0 = hasc0 ? (ynB0 - xpB0) : 1.0f;
        dcB1 = ynB1 - xpB1; dcB16 = ynB16 - xpB16;
        xpA0 = ynA0; xpA1 = ynA1; xpA16 = ynA16;
        xpB0 = ynB0; xpB1 = ynB1; xpB16 = ynB16;
    }
}

// out = gelu_exact(zT) @ w_proj + b_proj ; mask = 0
__global__ void ncde_proj(const float* __restrict__ zT,
                          const float* __restrict__ w_proj, const float* __restrict__ b_proj,
                          float* __restrict__ out, float* __restrict__ mask)
{
    __shared__ float gz[16][64];
    const int blk = blockIdx.x;
    const int tid = threadIdx.x;
    const int r16 = tid >> 4, f = tid & 15;
    const int row0 = blk * 16;

    #pragma unroll
    for (int i = 0; i < 4; ++i) {
        int idx = tid + i * 256;
        int r = idx >> 6, k = idx & 63;
        float zv = zT[(size_t)(row0 + r) * HH + k];
        gz[r][k] = 0.5f * zv * (1.0f + erff(zv * 0.70710678118654752f));
    }
    __syncthreads();

    float acc = b_proj[f];
    #pragma unroll
    for (int k = 0; k < 64; ++k)
        acc = fmaf(gz[r16][k], w_proj[k * FF + f], acc);
    out[(size_t)(row0 + r16) * FF + f] = acc;
    if (f == 0) mask[row0 + r16] = 0.0f;
}

extern "C" void kernel_launch(void* const* d_in, const int* in_sizes, int n_in,
                              void* d_out, int out_size, void* d_ws, size_t ws_size,
                              hipStream_t stream)
{
    (void)in_sizes; (void)n_in; (void)d_ws; (void)ws_size; (void)out_size;
    const float* x      = (const float*)d_in[0];
    const float* wi1    = (const float*)d_in[1];
    const float* bi1    = (const float*)d_in[2];
    const float* wi2    = (const float*)d_in[3];
    const float* bi2    = (const float*)d_in[4];
    const float* w_in   = (const float*)d_in[5];
    const float* b_in   = (const float*)d_in[6];
    const float* w_hid  = (const float*)d_in[7];
    const float* b_hid  = (const float*)d_in[8];
    const float* w_out  = (const float*)d_in[9];
    const float* b_out  = (const float*)d_in[10];
    const float* w_proj = (const float*)d_in[11];
    const float* b_proj = (const float*)d_in[12];

    float* zT   = (float*)d_out;                       // B*T*H
    float* outp = zT + (size_t)BB * TT * HH;           // B*T*F
    float* mask = outp + (size_t)BB * TT * FF;         // B*T

    ncde_main<<<dim3(BB / 2), dim3(512), 0, stream>>>(
        x, wi1, bi1, wi2, bi2, w_in, b_in, w_hid, b_hid, w_out, b_out, zT);
    ncde_proj<<<dim3((BB * TT) / 16), dim3(256), 0, stream>>>(
        zT, w_proj, b_proj, outp, mask);
}